// Round 8
// baseline (838.779 us; speedup 1.0000x reference)
//
#include <hip/hip_runtime.h>
#include <hip/hip_bf16.h>
#include <stdint.h>

#define M_DIM 8192
#define K_DIM 4096
#define N_DIM 11008

typedef __attribute__((ext_vector_type(8))) short bf16x8;
typedef __attribute__((ext_vector_type(4))) float f32x4;
typedef __attribute__((ext_vector_type(16))) float f32x16;
typedef __attribute__((ext_vector_type(4))) unsigned int uint4v;

__device__ __forceinline__ unsigned short f2bf(float f) {
    __hip_bfloat16 h = __float2bfloat16(f);
    return __builtin_bit_cast(unsigned short, h);
}

__device__ __forceinline__ void gload_lds16(const unsigned short* g, unsigned short* l) {
    __builtin_amdgcn_global_load_lds(
        (const __attribute__((address_space(1))) void*)g,
        (__attribute__((address_space(3))) void*)l,
        16, 0, 0);
}

__device__ __forceinline__ unsigned lds_addr(const unsigned short* p) {
    return (unsigned)(uintptr_t)(const __attribute__((address_space(3))) unsigned short*)p;
}

// inline-asm ds_read_b128 with immediate offset; invisible to the compiler's
// LDS dependency tracker — hand-placed counted lgkm waits order the consumers.
#define DSRI(dst, a, OFF) asm volatile("ds_read_b128 %0, %1 offset:%2" \
    : "=v"(dst) : "v"(a), "n"(OFF) : "memory")

// counted lgkm wait + scheduler fence (rule #18).
#define LGKM(N) do { \
    asm volatile("s_waitcnt lgkmcnt(" #N ")" ::: "memory"); \
    __builtin_amdgcn_sched_barrier(0); \
} while (0)
#define BAR() do { __builtin_amdgcn_s_barrier(); asm volatile("" ::: "memory"); } while (0)

// ---------------------------------------------------------------------------
// Kernel 1: fused column-gather + fp32->bf16 convert.
// ---------------------------------------------------------------------------
__global__ void permute_x_kernel(const float* __restrict__ x,
                                 const int* __restrict__ ci,
                                 unsigned short* __restrict__ xg) {
    int idx = blockIdx.x * 256 + threadIdx.x;
    int64_t base = (int64_t)idx * 4;
    int m = (int)(base >> 12);        // K=4096
    int k = (int)(base & 4095);
    const float* xrow = x + ((int64_t)m << 12);
    int4 c4 = *reinterpret_cast<const int4*>(ci + k);
    ushort4 o;
    o.x = f2bf(xrow[c4.x]);
    o.y = f2bf(xrow[c4.y]);
    o.z = f2bf(xrow[c4.z]);
    o.w = f2bf(xrow[c4.w]);
    *reinterpret_cast<ushort4*>(xg + base) = o;
}

// ---------------------------------------------------------------------------
// Kernel 2: int4 unpack + per-group scale + transpose to wT[N][K] bf16.
// ---------------------------------------------------------------------------
__global__ void dequant_w_kernel(const int* __restrict__ wp,
                                 const float* __restrict__ scales,
                                 unsigned short* __restrict__ wT) {
    __shared__ unsigned short tile[64][65];
    int n0 = blockIdx.x * 64;
    int k0 = blockIdx.y * 64;
    int g = k0 >> 7;
    int t = threadIdx.x;
    int col = t & 63;
    int r0 = t >> 6;
    float s = scales[(int64_t)g * N_DIM + n0 + col];
    int pr0 = k0 >> 1;
#pragma unroll
    for (int i = 0; i < 8; ++i) {
        int row = r0 + i * 4;
        int p = wp[(int64_t)(pr0 + row) * N_DIM + n0 + col];
        tile[2 * row][col]     = f2bf((float)((p & 15) - 8) * s);
        tile[2 * row + 1][col] = f2bf((float)(((p >> 4) & 15) - 8) * s);
    }
    __syncthreads();
    int nl = t >> 2;
    int kk0 = (t & 3) << 4;
    unsigned short vals[16];
#pragma unroll
    for (int j = 0; j < 16; ++j) vals[j] = tile[kk0 + j][nl];
    uint4v* dst = reinterpret_cast<uint4v*>(wT + (int64_t)(n0 + nl) * K_DIM + k0 + kk0);
    dst[0] = *reinterpret_cast<const uint4v*>(&vals[0]);
    dst[1] = *reinterpret_cast<const uint4v*>(&vals[8]);
}

// ---------------------------------------------------------------------------
// Kernel 3: bf16 GEMM, 256x256 tile, 3-buffer rotation (BK=32), 32x32x16 MFMA
// (this round: shape switch — pipe floor −17%, half the MFMA instructions,
// identical LDS traffic).
//
// LDS 96 KiB = 3 bufs x {A [256 r][32 k], B [256 r][32 k]} as round 7.
// T2 swizzle identical: phys = lin ^ ((row&6)<<3); row&6 == lane&6 for the
// 32-row fragment map too, so read XOR and staging source-perm are unchanged.
// kf1 (+32 B = bit 5) collides with the XOR bits -> separate pre-XORed base
// ((lin+32)^xr) instead of an immediate. m/n strides (2048) and buf strides
// (32768/65536) are XOR-safe immediates.
//
// Fragments (mfma_f32_32x32x16_bf16): per wave 128x64 out = 4 m-frags x
// 2 n-frags, 2 k-frags per tile. A-frag: lane reads row=mf*32+(lane&31),
// k=8*(lane>>5)+kf*16, 8 consecutive bf16 = 1 ds_read_b128; B symmetric.
// C/D: col=lane&31, row=(reg&3)+8*(reg>>2)+4*(lane>>5) [m101, verified].
//
// Per K-tile j (buf B=j%3): 2 phases, read sets K0_j/K1_j of 6 reads each.
//  P1: issue K1_j; stage A_{j+2}; LGKM(6) [drains K0_j, issued prev phase];
//      8 MFMA (kf0); vmcnt(2); BAR.
//  P2: issue K0_{j+1}; stage B_{j+2}; LGKM(6) [drains K1_j]; 8 MFMA (kf1); BAR.
// vmcnt(2)/overwrite ledgers identical to round 7 (stage placement unchanged).
// ---------------------------------------------------------------------------

__device__ __forceinline__ void mfma_tile(f32x16 (&acc)[4][2], const bf16x8 (&av)[4],
                                          const bf16x8 (&bv)[2]) {
    __builtin_amdgcn_s_setprio(1);
#pragma unroll
    for (int m = 0; m < 4; ++m)
#pragma unroll
        for (int n = 0; n < 2; ++n)
            acc[m][n] = __builtin_amdgcn_mfma_f32_32x32x16_bf16(
                av[m], bv[n], acc[m][n], 0, 0, 0);
    __builtin_amdgcn_s_setprio(0);
}

// read one k-frag set (6 x ds_read_b128): A m0-3 + B n0-1 of buf BUF.
// aB/bB are the kf-specific pre-XORed bases (buf0/1); aB2/bB2 the buf2 ones.
template <int BUF>
__device__ __forceinline__ void read_set(bf16x8 (&a)[4], bf16x8 (&b)[2],
                                         unsigned aB, unsigned aB2,
                                         unsigned bB, unsigned bB2) {
    const unsigned ad = (BUF < 2) ? aB : aB2;
    const unsigned bd = (BUF < 2) ? bB : bB2;
    constexpr int bo = (BUF < 2) ? BUF * 32768 : 0;
    DSRI(a[0], ad, bo + 0);
    DSRI(a[1], ad, bo + 2048);
    DSRI(a[2], ad, bo + 4096);
    DSRI(a[3], ad, bo + 6144);
    DSRI(b[0], bd, bo + 0);
    DSRI(b[1], bd, bo + 2048);
}

// stage one 16 KiB region (256 rows x 32 k) of K-tile t into buf DBUF.
template <int DBUF, int ISB>
__device__ __forceinline__ void stage2(const unsigned short* p0, const unsigned short* p1,
                                       int t, unsigned short* lds, int wLds) {
    const unsigned short* s0 = p0 + t * 32;
    const unsigned short* s1 = p1 + t * 32;
    unsigned short* d = lds + DBUF * 16384 + ISB * 8192 + wLds;
    gload_lds16(s0, d);
    gload_lds16(s1, d + 512);
}

// one K-tile: B=buf, BN=(B+1)%3, BS=(B+2)%3; CA_/CB_ = this tile's kf0 frags
// (already issued), NA_/NB_ = next tile's kf0 frags; tt = tile staged (j+2).
#define PH_TILE(B, BN, BS, CA_, CB_, NA_, NB_, tt)                        \
    do {                                                                  \
        read_set<B>(aZ, bZ, aK1, aK1_2, bK1, bK1_2);                      \
        stage2<BS, 0>(pA0, pA1, (tt), lds, wLds);                         \
        LGKM(6);                                                          \
        mfma_tile(acc, CA_, CB_);                                         \
        asm volatile("s_waitcnt vmcnt(2)" ::: "memory");                  \
        BAR();                                                            \
        read_set<BN>(NA_, NB_, aK0, aK0_2, bK0, bK0_2);                   \
        stage2<BS, 1>(pB0, pB1, (tt), lds, wLds);                         \
        LGKM(6);                                                          \
        mfma_tile(acc, aZ, bZ);                                           \
        BAR();                                                            \
    } while (0)

__global__ __launch_bounds__(512, 2)
void gemm_kernel(const unsigned short* __restrict__ A,
                 const unsigned short* __restrict__ BT,
                 const float* __restrict__ bias,
                 float* __restrict__ C) {
    __shared__ unsigned short lds[49152];   // 96 KiB: 3 bufs x 32 KiB

    constexpr int NT = N_DIM / 256;  // 43
    int wg = blockIdx.x, nwg = gridDim.x;
    int q = nwg >> 3, r = nwg & 7;
    int xcd = wg & 7, li = wg >> 3;
    int swz = (xcd < r ? xcd * (q + 1) : r * (q + 1) + (xcd - r) * q) + li;
    int by = swz / NT, bx = swz - by * NT;
    int brow = by << 8, bcol = bx << 8;

    int t = threadIdx.x;
    int lane = t & 63, w = t >> 6;
    int wr = w >> 2, wc = w & 3;           // 2 x 4 wave grid
    int l31 = lane & 31, hi = lane >> 5;

    // T2 bank swizzle (identical to r7): read XOR on byte bits 4-5.
    const unsigned xr = (unsigned)((lane & 6) << 3);
    const int riw = lane >> 2;
    const int s8 = ((lane & 3) ^ ((lane >> 3) & 3)) << 3;
    const int w32 = w * 32, wLds = w * 1024;

    const unsigned ldsB = lds_addr(lds);
    const unsigned lin_a = (unsigned)((wr * 128 + l31) * 64 + hi * 16);
    const unsigned lin_b = (unsigned)((wc * 64 + l31) * 64 + hi * 16);
    // kf-specific bases: XOR applied AFTER adding the kf byte offset (bit 5
    // collides with the swizzle bits, so it can't live in the immediate).
    const unsigned aK0 = ldsB + (lin_a ^ xr);
    const unsigned aK1 = ldsB + ((lin_a + 32) ^ xr);
    const unsigned bK0 = ldsB + 16384u + (lin_b ^ xr);
    const unsigned bK1 = ldsB + 16384u + ((lin_b + 32) ^ xr);
    const unsigned aK0_2 = aK0 + 65536, aK1_2 = aK1 + 65536;
    const unsigned bK0_2 = bK0 + 65536, bK1_2 = bK1 + 65536;

    // staging source pointers (row slice fixed per thread; k via t*32)
    const unsigned short* pA0 = A + (int64_t)(brow + w32 + riw) * K_DIM + s8;
    const unsigned short* pA1 = pA0 + 16 * K_DIM;
    const unsigned short* pB0 = BT + (int64_t)(bcol + w32 + riw) * K_DIM + s8;
    const unsigned short* pB1 = pB0 + 16 * K_DIM;

    f32x16 acc[4][2];
#pragma unroll
    for (int m = 0; m < 4; ++m)
#pragma unroll
        for (int n = 0; n < 2; ++n)
#pragma unroll
            for (int j = 0; j < 16; ++j) acc[m][n][j] = 0.f;

    bf16x8 aX[4], bX[2], aY[4], bY[2], aZ[4], bZ[2];

    // ---- prologue: stage tiles 0,1 into bufs 0,1; confirm buf0; pre-issue
    // K0_0 (color X). Leaves {A1,B1} outstanding = induction state.
    stage2<0, 0>(pA0, pA1, 0, lds, wLds);
    stage2<0, 1>(pB0, pB1, 0, lds, wLds);
    stage2<1, 0>(pA0, pA1, 1, lds, wLds);
    stage2<1, 1>(pB0, pB1, 1, lds, wLds);
    asm volatile("s_waitcnt vmcnt(4)" ::: "memory");
    BAR();
    read_set<0>(aX, bX, aK0, aK0_2, bK0, bK0_2);

#pragma unroll 1
    for (int body = 0; body < 21; ++body) {
        const int t2 = body * 6 + 2;
        PH_TILE(0, 1, 2, aX, bX, aY, bY, t2);       // tile 6b+0
        PH_TILE(1, 2, 0, aY, bY, aX, bX, t2 + 1);   // tile 6b+1
        PH_TILE(2, 0, 1, aX, bX, aY, bY, t2 + 2);   // tile 6b+2
        PH_TILE(0, 1, 2, aY, bY, aX, bX, t2 + 3);   // tile 6b+3
        PH_TILE(1, 2, 0, aX, bX, aY, bY, t2 + 4);   // tile 6b+4
        PH_TILE(2, 0, 1, aY, bY, aX, bX, t2 + 5);   // tile 6b+5
    }

    // ---- tail: tiles 126 (buf0, X) and 127 (buf1, Y), no stages.
    read_set<0>(aZ, bZ, aK1, aK1_2, bK1, bK1_2);
    LGKM(6);
    mfma_tile(acc, aX, bX);
    asm volatile("s_waitcnt vmcnt(0)" ::: "memory");   // drain A_127,B_127
    BAR();
    read_set<1>(aY, bY, aK0, aK0_2, bK0, bK0_2);
    LGKM(6);
    mfma_tile(acc, aZ, bZ);
    BAR();
    read_set<1>(aZ, bZ, aK1, aK1_2, bK1, bK1_2);
    LGKM(6);
    mfma_tile(acc, aY, bY);
    LGKM(0);
    mfma_tile(acc, aZ, bZ);

    // ---- epilogue: 32x32 C/D layout col=lane&31,
    // row = (reg&3) + 8*(reg>>2) + 4*(lane>>5) ----
    int orow0 = brow + wr * 128 + 4 * hi;
    int ocol0 = bcol + wc * 64 + l31;
#pragma unroll
    for (int n = 0; n < 2; ++n) {
        int col = ocol0 + n * 32;
        float bval = bias[col];
#pragma unroll
        for (int m = 0; m < 4; ++m) {
            int rbase = orow0 + m * 32;
#pragma unroll
            for (int j = 0; j < 16; ++j) {
                int row = rbase + (j & 3) + 8 * (j >> 2);
                C[(int64_t)row * N_DIM + col] = acc[m][n][j] + bval;
            }
        }
    }
}

extern "C" void kernel_launch(void* const* d_in, const int* in_sizes, int n_in,
                              void* d_out, int out_size, void* d_ws, size_t ws_size,
                              hipStream_t stream) {
    const float* x      = (const float*)d_in[0];
    const int* ci       = (const int*)d_in[1];
    const int* wp       = (const int*)d_in[2];
    const float* scales = (const float*)d_in[3];
    const float* bias   = (const float*)d_in[4];
    float* out          = (float*)d_out;

    const size_t wT_bytes = (size_t)N_DIM * K_DIM * 2;
    unsigned short* wT = (unsigned short*)d_ws;
    unsigned short* xg = wT + (size_t)N_DIM * K_DIM;

    size_t cap = (ws_size > wT_bytes) ? (ws_size - wT_bytes) : 0;
    int max_rows = (int)(cap / ((size_t)K_DIM * 2));
    int chunk_rows = (max_rows / 256) * 256;
    if (chunk_rows <= 0) chunk_rows = 256;      // best effort
    if (chunk_rows > M_DIM) chunk_rows = M_DIM;

    dequant_w_kernel<<<dim3(N_DIM / 64, K_DIM / 64), 256, 0, stream>>>(wp, scales, wT);

    for (int m0 = 0; m0 < M_DIM; m0 += chunk_rows) {
        int rows = M_DIM - m0 < chunk_rows ? M_DIM - m0 : chunk_rows;
        int pgrid = (int)(((int64_t)rows * K_DIM) / (4 * 256));
        permute_x_kernel<<<pgrid, 256, 0, stream>>>(
            x + (int64_t)m0 * K_DIM, ci, xg);
        int grid = (rows / 256) * (N_DIM / 256);
        gemm_kernel<<<grid, 512, 0, stream>>>(
            xg, wT, bias, out + (int64_t)m0 * N_DIM);
    }
}

// Round 9
// 832.316 us; speedup vs baseline: 1.0078x; 1.0078x over previous
//
#include <hip/hip_runtime.h>
#include <hip/hip_bf16.h>
#include <stdint.h>

#define M_DIM 8192
#define K_DIM 4096
#define N_DIM 11008

typedef __attribute__((ext_vector_type(8))) short bf16x8;
typedef __attribute__((ext_vector_type(4))) float f32x4;
typedef __attribute__((ext_vector_type(16))) float f32x16;
typedef __attribute__((ext_vector_type(4))) unsigned int uint4v;

__device__ __forceinline__ unsigned short f2bf(float f) {
    __hip_bfloat16 h = __float2bfloat16(f);
    return __builtin_bit_cast(unsigned short, h);
}

__device__ __forceinline__ void gload_lds16(const unsigned short* g, unsigned short* l) {
    __builtin_amdgcn_global_load_lds(
        (const __attribute__((address_space(1))) void*)g,
        (__attribute__((address_space(3))) void*)l,
        16, 0, 0);
}

__device__ __forceinline__ unsigned lds_addr(const unsigned short* p) {
    return (unsigned)(uintptr_t)(const __attribute__((address_space(3))) unsigned short*)p;
}

// inline-asm ds_read_b128 with immediate offset; invisible to the compiler's
// LDS dependency tracker — hand-placed counted lgkm waits order the consumers.
#define DSRI(dst, a, OFF) asm volatile("ds_read_b128 %0, %1 offset:%2" \
    : "=v"(dst) : "v"(a), "n"(OFF) : "memory")

// counted lgkm wait + scheduler fence (rule #18).
#define LGKM(N) do { \
    asm volatile("s_waitcnt lgkmcnt(" #N ")" ::: "memory"); \
    __builtin_amdgcn_sched_barrier(0); \
} while (0)
#define BAR() do { __builtin_amdgcn_s_barrier(); asm volatile("" ::: "memory"); } while (0)

// ---------------------------------------------------------------------------
// Kernel 1: fused column-gather + fp32->bf16 convert.
// ---------------------------------------------------------------------------
__global__ void permute_x_kernel(const float* __restrict__ x,
                                 const int* __restrict__ ci,
                                 unsigned short* __restrict__ xg) {
    int idx = blockIdx.x * 256 + threadIdx.x;
    int64_t base = (int64_t)idx * 4;
    int m = (int)(base >> 12);        // K=4096
    int k = (int)(base & 4095);
    const float* xrow = x + ((int64_t)m << 12);
    int4 c4 = *reinterpret_cast<const int4*>(ci + k);
    ushort4 o;
    o.x = f2bf(xrow[c4.x]);
    o.y = f2bf(xrow[c4.y]);
    o.z = f2bf(xrow[c4.z]);
    o.w = f2bf(xrow[c4.w]);
    *reinterpret_cast<ushort4*>(xg + base) = o;
}

// ---------------------------------------------------------------------------
// Kernel 2: int4 unpack + per-group scale + transpose to wT[N][K] bf16.
// ---------------------------------------------------------------------------
__global__ void dequant_w_kernel(const int* __restrict__ wp,
                                 const float* __restrict__ scales,
                                 unsigned short* __restrict__ wT) {
    __shared__ unsigned short tile[64][65];
    int n0 = blockIdx.x * 64;
    int k0 = blockIdx.y * 64;
    int g = k0 >> 7;
    int t = threadIdx.x;
    int col = t & 63;
    int r0 = t >> 6;
    float s = scales[(int64_t)g * N_DIM + n0 + col];
    int pr0 = k0 >> 1;
#pragma unroll
    for (int i = 0; i < 8; ++i) {
        int row = r0 + i * 4;
        int p = wp[(int64_t)(pr0 + row) * N_DIM + n0 + col];
        tile[2 * row][col]     = f2bf((float)((p & 15) - 8) * s);
        tile[2 * row + 1][col] = f2bf((float)(((p >> 4) & 15) - 8) * s);
    }
    __syncthreads();
    int nl = t >> 2;
    int kk0 = (t & 3) << 4;
    unsigned short vals[16];
#pragma unroll
    for (int j = 0; j < 16; ++j) vals[j] = tile[kk0 + j][nl];
    uint4v* dst = reinterpret_cast<uint4v*>(wT + (int64_t)(n0 + nl) * K_DIM + k0 + kk0);
    dst[0] = *reinterpret_cast<const uint4v*>(&vals[0]);
    dst[1] = *reinterpret_cast<const uint4v*>(&vals[8]);
}

// ---------------------------------------------------------------------------
// Kernel 3: bf16 GEMM, 256x256 tile, 3-buffer rotation (BK=32), 32x32x16 MFMA.
// This round: EXTENDED bank swizzle — add row-bit-4 term.
//
// Round-8 post-mortem: SQ_LDS_BANK_CONFLICT returned at exactly r3/r4's value
// (4 cyc/read) after the 16x16->32x32 shape switch, though the old swizzle is
// uniform over every CONTIGUOUS lane group. Inference: the LDS service
// grouping is transposed quarter-waves {l, l+16, l+32, l+48}. In the 32x32
// map (row=lane&31, k=lane>>5) lanes l and l+16 differ only in row BIT 4,
// which the old swizzle never maps to bank bits -> pairwise collision.
//
// New swizzle: phys = lin ^ ((row&6)<<3) ^ ((row&16)<<1).
// quad(lane) = (r0, r2^r4, r1^hi): distinct within contiguous-8 groups AND
// within {l,l+16,l+32,l+48}. Read side: row&16 == lane&16 for both A and B
// (wr*128/wc*64/n*32 don't touch bit 4) -> folds into per-lane base XOR.
// Write side (rule #21): staging row = w*32 + j*16 + (l>>2) -> row&16 = j;
// the j=1 gload's SOURCE column gets an extra ^16 elements (4-lane row
// coverage preserved -> coalescing unchanged). kf1 (+32B) stays a separate
// pre-XORed base, so no immediate collides with XOR bits 4-5.
//
// Everything else identical to round 8 (schedule, ledgers, epilogue):
//  P1: issue K1_j; stage A_{j+2}; LGKM(6); 8 MFMA (kf0); vmcnt(2); BAR.
//  P2: issue K0_{j+1}; stage B_{j+2}; LGKM(6); 8 MFMA (kf1); BAR.
// ---------------------------------------------------------------------------

__device__ __forceinline__ void mfma_tile(f32x16 (&acc)[4][2], const bf16x8 (&av)[4],
                                          const bf16x8 (&bv)[2]) {
    __builtin_amdgcn_s_setprio(1);
#pragma unroll
    for (int m = 0; m < 4; ++m)
#pragma unroll
        for (int n = 0; n < 2; ++n)
            acc[m][n] = __builtin_amdgcn_mfma_f32_32x32x16_bf16(
                av[m], bv[n], acc[m][n], 0, 0, 0);
    __builtin_amdgcn_s_setprio(0);
}

// read one k-frag set (6 x ds_read_b128): A m0-3 + B n0-1 of buf BUF.
template <int BUF>
__device__ __forceinline__ void read_set(bf16x8 (&a)[4], bf16x8 (&b)[2],
                                         unsigned aB, unsigned aB2,
                                         unsigned bB, unsigned bB2) {
    const unsigned ad = (BUF < 2) ? aB : aB2;
    const unsigned bd = (BUF < 2) ? bB : bB2;
    constexpr int bo = (BUF < 2) ? BUF * 32768 : 0;
    DSRI(a[0], ad, bo + 0);
    DSRI(a[1], ad, bo + 2048);
    DSRI(a[2], ad, bo + 4096);
    DSRI(a[3], ad, bo + 6144);
    DSRI(b[0], bd, bo + 0);
    DSRI(b[1], bd, bo + 2048);
}

// stage one 16 KiB region (256 rows x 32 k) of K-tile t into buf DBUF.
// p0 = rows 0-15 slice (source col perm s8), p1 = rows 16-31 slice (s8^16).
template <int DBUF, int ISB>
__device__ __forceinline__ void stage2(const unsigned short* p0, const unsigned short* p1,
                                       int t, unsigned short* lds, int wLds) {
    const unsigned short* s0 = p0 + t * 32;
    const unsigned short* s1 = p1 + t * 32;
    unsigned short* d = lds + DBUF * 16384 + ISB * 8192 + wLds;
    gload_lds16(s0, d);
    gload_lds16(s1, d + 512);
}

// one K-tile: B=buf, BN=(B+1)%3, BS=(B+2)%3; CA_/CB_ = this tile's kf0 frags
// (already issued), NA_/NB_ = next tile's kf0 frags; tt = tile staged (j+2).
#define PH_TILE(B, BN, BS, CA_, CB_, NA_, NB_, tt)                        \
    do {                                                                  \
        read_set<B>(aZ, bZ, aK1, aK1_2, bK1, bK1_2);                      \
        stage2<BS, 0>(pA0, pA1, (tt), lds, wLds);                         \
        LGKM(6);                                                          \
        mfma_tile(acc, CA_, CB_);                                         \
        asm volatile("s_waitcnt vmcnt(2)" ::: "memory");                  \
        BAR();                                                            \
        read_set<BN>(NA_, NB_, aK0, aK0_2, bK0, bK0_2);                   \
        stage2<BS, 1>(pB0, pB1, (tt), lds, wLds);                         \
        LGKM(6);                                                          \
        mfma_tile(acc, aZ, bZ);                                           \
        BAR();                                                            \
    } while (0)

__global__ __launch_bounds__(512, 2)
void gemm_kernel(const unsigned short* __restrict__ A,
                 const unsigned short* __restrict__ BT,
                 const float* __restrict__ bias,
                 float* __restrict__ C) {
    __shared__ unsigned short lds[49152];   // 96 KiB: 3 bufs x 32 KiB

    constexpr int NT = N_DIM / 256;  // 43
    int wg = blockIdx.x, nwg = gridDim.x;
    int q = nwg >> 3, r = nwg & 7;
    int xcd = wg & 7, li = wg >> 3;
    int swz = (xcd < r ? xcd * (q + 1) : r * (q + 1) + (xcd - r) * q) + li;
    int by = swz / NT, bx = swz - by * NT;
    int brow = by << 8, bcol = bx << 8;

    int t = threadIdx.x;
    int lane = t & 63, w = t >> 6;
    int wr = w >> 2, wc = w & 3;           // 2 x 4 wave grid
    int l31 = lane & 31, hi = lane >> 5;

    // Extended bank swizzle: bits 4-5 from row bits 1-2, bit 5 from row bit 4.
    const unsigned xr = (unsigned)(((lane & 6) << 3) ^ ((lane & 16) << 1));
    const int riw = lane >> 2;
    const int s8 = ((lane & 3) ^ ((lane >> 3) & 3)) << 3;   // j=0 source perm
    const int w32 = w * 32, wLds = w * 1024;

    const unsigned ldsB = lds_addr(lds);
    const unsigned lin_a = (unsigned)((wr * 128 + l31) * 64 + hi * 16);
    const unsigned lin_b = (unsigned)((wc * 64 + l31) * 64 + hi * 16);
    // kf-specific bases: XOR applied AFTER adding the kf byte offset (bit 5
    // collides with the swizzle bits, so it can't live in the immediate).
    const unsigned aK0 = ldsB + (lin_a ^ xr);
    const unsigned aK1 = ldsB + ((lin_a + 32) ^ xr);
    const unsigned bK0 = ldsB + 16384u + (lin_b ^ xr);
    const unsigned bK1 = ldsB + 16384u + ((lin_b + 32) ^ xr);
    const unsigned aK0_2 = aK0 + 65536, aK1_2 = aK1 + 65536;
    const unsigned bK0_2 = bK0 + 65536, bK1_2 = bK1 + 65536;

    // staging source pointers. Row slice 0-15 uses col perm s8; row slice
    // 16-31 (staging row bit4 = 1) uses s8^16 (write-side inverse of the
    // new XOR term).
    const unsigned short* pA0 = A + (int64_t)(brow + w32 + riw) * K_DIM + s8;
    const unsigned short* pA1 = A + (int64_t)(brow + w32 + 16 + riw) * K_DIM + (s8 ^ 16);
    const unsigned short* pB0 = BT + (int64_t)(bcol + w32 + riw) * K_DIM + s8;
    const unsigned short* pB1 = BT + (int64_t)(bcol + w32 + 16 + riw) * K_DIM + (s8 ^ 16);

    f32x16 acc[4][2];
#pragma unroll
    for (int m = 0; m < 4; ++m)
#pragma unroll
        for (int n = 0; n < 2; ++n)
#pragma unroll
            for (int j = 0; j < 16; ++j) acc[m][n][j] = 0.f;

    bf16x8 aX[4], bX[2], aY[4], bY[2], aZ[4], bZ[2];

    // ---- prologue: stage tiles 0,1 into bufs 0,1; confirm buf0; pre-issue
    // K0_0 (color X). Leaves {A1,B1} outstanding = induction state.
    stage2<0, 0>(pA0, pA1, 0, lds, wLds);
    stage2<0, 1>(pB0, pB1, 0, lds, wLds);
    stage2<1, 0>(pA0, pA1, 1, lds, wLds);
    stage2<1, 1>(pB0, pB1, 1, lds, wLds);
    asm volatile("s_waitcnt vmcnt(4)" ::: "memory");
    BAR();
    read_set<0>(aX, bX, aK0, aK0_2, bK0, bK0_2);

#pragma unroll 1
    for (int body = 0; body < 21; ++body) {
        const int t2 = body * 6 + 2;
        PH_TILE(0, 1, 2, aX, bX, aY, bY, t2);       // tile 6b+0
        PH_TILE(1, 2, 0, aY, bY, aX, bX, t2 + 1);   // tile 6b+1
        PH_TILE(2, 0, 1, aX, bX, aY, bY, t2 + 2);   // tile 6b+2
        PH_TILE(0, 1, 2, aY, bY, aX, bX, t2 + 3);   // tile 6b+3
        PH_TILE(1, 2, 0, aX, bX, aY, bY, t2 + 4);   // tile 6b+4
        PH_TILE(2, 0, 1, aY, bY, aX, bX, t2 + 5);   // tile 6b+5
    }

    // ---- tail: tiles 126 (buf0, X) and 127 (buf1, Y), no stages.
    read_set<0>(aZ, bZ, aK1, aK1_2, bK1, bK1_2);
    LGKM(6);
    mfma_tile(acc, aX, bX);
    asm volatile("s_waitcnt vmcnt(0)" ::: "memory");   // drain A_127,B_127
    BAR();
    read_set<1>(aY, bY, aK0, aK0_2, bK0, bK0_2);
    LGKM(6);
    mfma_tile(acc, aZ, bZ);
    BAR();
    read_set<1>(aZ, bZ, aK1, aK1_2, bK1, bK1_2);
    LGKM(6);
    mfma_tile(acc, aY, bY);
    LGKM(0);
    mfma_tile(acc, aZ, bZ);

    // ---- epilogue: 32x32 C/D layout col=lane&31,
    // row = (reg&3) + 8*(reg>>2) + 4*(lane>>5) ----
    int orow0 = brow + wr * 128 + 4 * hi;
    int ocol0 = bcol + wc * 64 + l31;
#pragma unroll
    for (int n = 0; n < 2; ++n) {
        int col = ocol0 + n * 32;
        float bval = bias[col];
#pragma unroll
        for (int m = 0; m < 4; ++m) {
            int rbase = orow0 + m * 32;
#pragma unroll
            for (int j = 0; j < 16; ++j) {
                int row = rbase + (j & 3) + 8 * (j >> 2);
                C[(int64_t)row * N_DIM + col] = acc[m][n][j] + bval;
            }
        }
    }
}

extern "C" void kernel_launch(void* const* d_in, const int* in_sizes, int n_in,
                              void* d_out, int out_size, void* d_ws, size_t ws_size,
                              hipStream_t stream) {
    const float* x      = (const float*)d_in[0];
    const int* ci       = (const int*)d_in[1];
    const int* wp       = (const int*)d_in[2];
    const float* scales = (const float*)d_in[3];
    const float* bias   = (const float*)d_in[4];
    float* out          = (float*)d_out;

    const size_t wT_bytes = (size_t)N_DIM * K_DIM * 2;
    unsigned short* wT = (unsigned short*)d_ws;
    unsigned short* xg = wT + (size_t)N_DIM * K_DIM;

    size_t cap = (ws_size > wT_bytes) ? (ws_size - wT_bytes) : 0;
    int max_rows = (int)(cap / ((size_t)K_DIM * 2));
    int chunk_rows = (max_rows / 256) * 256;
    if (chunk_rows <= 0) chunk_rows = 256;      // best effort
    if (chunk_rows > M_DIM) chunk_rows = M_DIM;

    dequant_w_kernel<<<dim3(N_DIM / 64, K_DIM / 64), 256, 0, stream>>>(wp, scales, wT);

    for (int m0 = 0; m0 < M_DIM; m0 += chunk_rows) {
        int rows = M_DIM - m0 < chunk_rows ? M_DIM - m0 : chunk_rows;
        int pgrid = (int)(((int64_t)rows * K_DIM) / (4 * 256));
        permute_x_kernel<<<pgrid, 256, 0, stream>>>(
            x + (int64_t)m0 * K_DIM, ci, xg);
        int grid = (rows / 256) * (N_DIM / 256);
        gemm_kernel<<<grid, 512, 0, stream>>>(
            xg, wT, bias, out + (int64_t)m0 * N_DIM);
    }
}